// Round 14
// baseline (185.165 us; speedup 1.0000x reference)
//
#include <hip/hip_runtime.h>
#include <hip/hip_fp16.h>
#include <math.h>

namespace {
constexpr int   QUALITY = 8;
constexpr int   NPART   = 18000 * QUALITY * QUALITY;  // 1,152,000
constexpr int   NG      = 128 * QUALITY;              // 1024
constexpr int   NCELL   = NG * NG;                    // 1,048,576
constexpr int   CT      = 16;                         // gather tile side (cells)
constexpr int   NBT     = NG / CT;                    // 64
constexpr int   WROWS   = 18;                         // window rows (x0-2 .. x0+15)
constexpr int   WCOLS   = 18;                         // window cols (y0-2 .. y0+15)
constexpr int   CAP     = 768;                        // staged particles per tile
constexpr float DX      = 1.0f / (float)NG;
constexpr float INV_DX  = (float)NG;
constexpr float DT      = (float)(1e-4 / (double)QUALITY);
constexpr float MU0     = (float)(5000.0 / (2.0 * (1.0 + 0.2)));
constexpr float LAM0    = (float)(5000.0 * 0.2 / ((1.0 + 0.2) * (1.0 - 0.4)));
// stress scale divided by P_MASS (P_MASS cancels in gv = mom/mass):
constexpr float STRESS_RP  = (float)(-(1e-4 / 8.0) * 4.0 * 1024.0 * 1024.0);  // -52.4288
constexpr float GRAV_SCALE = (float)((1e-4 / 8.0) * 30.0);
constexpr float ATTR_SCALE = (float)((1e-4 / 8.0) * 100.0);

typedef int v4i __attribute__((ext_vector_type(4)));

__device__ __forceinline__ int2 base_of(float xx, float xy) {
    int bx = (int)floorf(xx * INV_DX - 0.5f);
    int by = (int)floorf(xy * INV_DX - 0.5f);
    bx = min(max(bx, 0), NG - 3);
    by = min(max(by, 0), NG - 3);
    return make_int2(bx, by);
}

__device__ __forceinline__ unsigned pack2h(float a, float b) {
    __half2 h = __floats2half2_rn(a, b);
    return *reinterpret_cast<unsigned*>(&h);
}
__device__ __forceinline__ float2 unpack2h(unsigned u) {
    __half2 h = *reinterpret_cast<__half2*>(&u);
    return __half22float2(h);
}

// quadratic B-spline weight, branchless: s = |fx - j|
__device__ __forceinline__ float bspline(float s) {
    s = fabsf(s);
    float a = 0.75f - s * s;
    float b = 1.5f - s;
    b = 0.5f * b * b;
    return (s < 0.5f) ? a : b;
}
}

// ---- K1: per-cell histogram; atomic return value IS the within-cell rank ----
__global__ __launch_bounds__(256)
void count_kernel(const float* __restrict__ x, int* __restrict__ cnt,
                  int* __restrict__ rank) {
    int p = blockIdx.x * blockDim.x + threadIdx.x;
    if (p >= NPART) return;
    const float2 xv = ((const float2*)x)[p];
    int2 b = base_of(xv.x, xv.y);
    rank[p] = atomicAdd(&cnt[b.x * NG + b.y], 1);
}

// ---- K2a: per-block (1024 cells) sums ----
__global__ __launch_bounds__(256)
void blocksum_kernel(const int* __restrict__ cnt, int* __restrict__ bsum) {
    __shared__ int sh[256];
    int t = threadIdx.x;
    int4 c = ((const int4*)cnt)[blockIdx.x * 256 + t];
    sh[t] = c.x + c.y + c.z + c.w;
    __syncthreads();
    for (int s = 128; s > 0; s >>= 1) {
        if (t < s) sh[t] += sh[t + s];
        __syncthreads();
    }
    if (t == 0) bsum[blockIdx.x] = sh[0];
}

// ---- K2b: exclusive scan of the 1024 block sums ----
__global__ __launch_bounds__(1024)
void scanb_kernel(const int* __restrict__ bsum, int* __restrict__ boff,
                  int* __restrict__ cell_start) {
    __shared__ int s[1024];
    int t = threadIdx.x;
    int v = bsum[t];
    s[t] = v;
    __syncthreads();
    for (int off = 1; off < 1024; off <<= 1) {
        int add = (t >= off) ? s[t - off] : 0;
        __syncthreads();
        s[t] += add;
        __syncthreads();
    }
    boff[t] = s[t] - v;
    if (t == 1023) cell_start[NCELL] = s[t];
}

// ---- K2c: per-block scan -> cell_start ----
__global__ __launch_bounds__(256)
void scanc_kernel(const int* __restrict__ cnt, const int* __restrict__ boff,
                  int* __restrict__ cell_start) {
    __shared__ int tsum[256];
    int t = threadIdx.x;
    int gbase4 = blockIdx.x * 256 + t;
    int4 c = ((const int4*)cnt)[gbase4];
    int s1 = c.x, s2 = s1 + c.y, s3 = s2 + c.z, tot = s3 + c.w;
    tsum[t] = tot;
    __syncthreads();
    for (int off = 1; off < 256; off <<= 1) {
        int add = (t >= off) ? tsum[t - off] : 0;
        __syncthreads();
        tsum[t] += add;
        __syncthreads();
    }
    int excl = tsum[t] - tot;
    int g = boff[blockIdx.x] + excl;
    ((int4*)cell_start)[gbase4] = make_int4(g, g + s1, g + s2, g + s3);
}

// ---- K3: fused physics + sorted 16B payload scatter (NO atomic: slot from rank) ----
// payload q.x: bits[13:0]=qx (fxx-0.5, 14b), [29:16]=qy, [31:30]=by&3 (unused now)
__global__ __launch_bounds__(256)
void physics_scatter_kernel(const float* __restrict__ x, const float* __restrict__ v,
                            const float* __restrict__ Cin, const float* __restrict__ Fin,
                            const float* __restrict__ Jpin, const int* __restrict__ mat,
                            const int* __restrict__ cell_start, const int* __restrict__ rank,
                            uint4* __restrict__ spay,
                            float* __restrict__ outF, float* __restrict__ outJp)
{
    int p = blockIdx.x * blockDim.x + threadIdx.x;
    if (p >= NPART) return;

    const float2 xv = ((const float2*)x)[p];
    const float2 vv = ((const float2*)v)[p];
    const float4 Cv = ((const float4*)Cin)[p];
    const float4 Fv = ((const float4*)Fin)[p];
    float xx = xv.x, xy = xv.y;
    float C00 = Cv.x, C01 = Cv.y, C10 = Cv.z, C11 = Cv.w;
    float F00 = Fv.x, F01 = Fv.y, F10 = Fv.z, F11 = Fv.w;

    // F = (I + DT*C) @ F
    float A00 = 1.0f + DT * C00, A01 = DT * C01, A10 = DT * C10, A11 = 1.0f + DT * C11;
    float G00 = A00 * F00 + A01 * F10;
    float G01 = A00 * F01 + A01 * F11;
    float G10 = A10 * F00 + A11 * F10;
    float G11 = A10 * F01 + A11 * F11;

    int m = mat[p];
    float Jp = Jpin[p];
    float h = fminf(fmaxf(expf(10.0f * (1.0f - Jp)), 0.1f), 5.0f);
    if (m == 1) h = 0.3f;
    float mu = (m == 0) ? 0.0f : MU0 * h;
    float la = LAM0 * h;

    // closed-form 2x2 SVD
    float Ee = 0.5f * (G00 + G11);
    float Hh = 0.5f * (G10 - G01);
    float Ff = 0.5f * (G00 - G11);
    float Gg = 0.5f * (G10 + G01);
    float Qq = sqrtf(Ee * Ee + Hh * Hh);
    float Rr = sqrtf(Ff * Ff + Gg * Gg);
    float s0 = Qq + Rr, s1 = Qq - Rr;
    float b1 = atan2f(Gg, Ff);
    float b2 = atan2f(Hh, Ee);
    float phi = 0.5f * (b1 + b2), th = 0.5f * (b1 - b2);
    float sphi, cphi, sth, cth;
    sincosf(phi, &sphi, &cphi);
    sincosf(th, &sth, &cth);

    float ns0 = s0, ns1 = s1;
    if (m == 2) {
        ns0 = fminf(fmaxf(s0, 1.0f - 2.5e-2f), 1.0f + 4.5e-3f);
        ns1 = fminf(fmaxf(s1, 1.0f - 2.5e-2f), 1.0f + 4.5e-3f);
        Jp = Jp * (s0 / ns0) * (s1 / ns1);
    }
    float J = ns0 * ns1;

    float FF00, FF01, FF10, FF11;
    if (m == 0) {
        float sj = sqrtf(J);
        FF00 = sj; FF01 = 0.0f; FF10 = 0.0f; FF11 = sj;
    } else if (m == 2) {
        FF00 = ns0 * cphi * cth + ns1 * sphi * sth;
        FF01 = ns0 * cphi * sth - ns1 * sphi * cth;
        FF10 = ns0 * sphi * cth - ns1 * cphi * sth;
        FF11 = ns0 * sphi * sth + ns1 * cphi * cth;
    } else {
        FF00 = G00; FF01 = G01; FF10 = G10; FF11 = G11;
    }

    // R = U V^T = rot(phi - th)
    float cr = cphi * cth + sphi * sth;
    float sr = sphi * cth - cphi * sth;

    float D00 = FF00 - cr,  D01 = FF01 + sr;
    float D10 = FF10 - sr,  D11 = FF11 - cr;
    float S00 = D00 * FF00 + D01 * FF01;
    float S01 = D00 * FF10 + D01 * FF11;
    float S10 = D10 * FF00 + D11 * FF01;
    float S11 = D10 * FF10 + D11 * FF11;
    float lj = la * J * (J - 1.0f);
    S00 = 2.0f * mu * S00 + lj;
    S01 = 2.0f * mu * S01;
    S10 = 2.0f * mu * S10;
    S11 = 2.0f * mu * S11 + lj;
    // affine / P_MASS  (P_MASS cancels in the grid normalize)
    float a00 = STRESS_RP * S00 + C00;
    float a01 = STRESS_RP * S01 + C01;
    float a10 = STRESS_RP * S10 + C10;
    float a11 = STRESS_RP * S11 + C11;

    ((float4*)outF)[p] = make_float4(FF00, FF01, FF10, FF11);
    outJp[p] = Jp;

    // fractional position (fx in [0.5,1.5)), 14-bit quantized
    float bxf = floorf(xx * INV_DX - 0.5f);
    float byf = floorf(xy * INV_DX - 0.5f);
    float fxx = xx * INV_DX - bxf;
    float fxy = xy * INV_DX - byf;
    unsigned qx = (unsigned)__float2int_rn((fxx - 0.5f) * 16383.0f);
    unsigned qy = (unsigned)__float2int_rn((fxy - 0.5f) * 16383.0f);

    int2 b = base_of(xx, xy);

    v4i payload;
    payload.x = (int)((qx & 0x3FFFu) | ((qy & 0x3FFFu) << 16) | (((unsigned)b.y & 3u) << 30));
    payload.y = (int)pack2h(vv.x, vv.y);
    payload.z = (int)pack2h(a00, a01);
    payload.w = (int)pack2h(a10, a11);

    int pos = cell_start[b.x * NG + b.y] + rank[p];   // no atomic
    __builtin_nontemporal_store(payload, (v4i*)&spay[pos]);
}

// ---- K4: tile-staged P2G gather + fused grid update ----
// Stage the 18x18 window's particles DECODED into LDS once; each cell then
// walks LDS slots (2 x ds_read_b128 + branchless bspline per visit).
__global__ __launch_bounds__(256)
void p2g_tile_kernel(const uint4* __restrict__ spay,
                     const int* __restrict__ cell_start,
                     const float* __restrict__ grav,
                     const float* __restrict__ astr,
                     const float* __restrict__ apos,
                     float* __restrict__ gv)
{
    __shared__ int   csA[WROWS * (WCOLS + 1)];   // raw cell_start window
    __shared__ int   offl[WROWS * (WCOLS + 1)];  // LDS slot offsets
    __shared__ int   rowbase[WROWS];
    __shared__ int   s_total;
    __shared__ float part[CAP * 8];              // fx_rel, fy_rel, vx, vy, a00,a01,a10,a11

    int tile = blockIdx.x;
    int x0 = (tile / NBT) * CT;
    int y0 = (tile % NBT) * CT;
    int tid = threadIdx.x;

    // phase 0a: load cell_start boundaries for the window
    for (int i = tid; i < WROWS * (WCOLS + 1); i += 256) {
        int wr = i / (WCOLS + 1), wc = i % (WCOLS + 1);
        int gr = x0 - 2 + wr;
        int c  = y0 - 2 + wc;
        int val = 0;
        if (gr >= 0 && gr < NG) {
            int cc = min(max(c, 0), NG);
            val = cell_start[gr * NG + cc];
        }
        csA[i] = val;
    }
    __syncthreads();

    // phase 0b: row bases (serial, tiny)
    if (tid == 0) {
        int base = 0;
        for (int wr = 0; wr < WROWS; ++wr) {
            rowbase[wr] = base;
            base += csA[wr * (WCOLS + 1) + WCOLS] - csA[wr * (WCOLS + 1)];
        }
        s_total = base;
    }
    __syncthreads();
    int total = s_total;
    bool staged = (total <= CAP);

    if (staged) {
        // phase 0c: offset table
        for (int i = tid; i < WROWS * (WCOLS + 1); i += 256) {
            int wr = i / (WCOLS + 1);
            offl[i] = rowbase[wr] + csA[i] - csA[wr * (WCOLS + 1)];
        }
        __syncthreads();
        // phase 0d: stage + decode particles per window cell
        for (int ci = tid; ci < WROWS * WCOLS; ci += 256) {
            int wr = ci / WCOLS, wc = ci % WCOLS;
            int sbeg = csA[wr * (WCOLS + 1) + wc];
            int send = csA[wr * (WCOLS + 1) + wc + 1];
            int slot = offl[wr * (WCOLS + 1) + wc];
            float frow = (float)wr, fcol = (float)wc;
            for (int t = sbeg; t < send; ++t, ++slot) {
                uint4 q = spay[t];
                float fx_rel = frow + 0.5f + (float)(q.x & 0x3FFFu) * (1.0f / 16383.0f);
                float fy_rel = fcol + 0.5f + (float)((q.x >> 16) & 0x3FFFu) * (1.0f / 16383.0f);
                float2 vv = unpack2h(q.y);
                float2 aA = unpack2h(q.z);
                float2 aB = unpack2h(q.w);
                float* pp = &part[slot * 8];
                ((float4*)pp)[0] = make_float4(fx_rel, fy_rel, vv.x, vv.y);
                ((float4*)pp)[1] = make_float4(aA.x, aA.y, aB.x, aB.y);
            }
        }
    }
    __syncthreads();

    int tr = tid / CT, tc = tid % CT;
    int cx = x0 + tr, cy = y0 + tc;
    float svx = 0.0f, svy = 0.0f, sw = 0.0f;

    if (staged) {
        float cxw = (float)(tr + 2);      // cell position in window coords
        float cyw = (float)(tc + 2);
        #pragma unroll
        for (int d = 0; d < 3; ++d) {
            int wr = tr + d;
            int sbeg = offl[wr * (WCOLS + 1) + tc];
            int send = offl[wr * (WCOLS + 1) + tc + 3];
            for (int s = sbeg; s < send; ++s) {
                const float* pp = &part[s * 8];
                float4 P0 = ((const float4*)pp)[0];
                float4 P1 = ((const float4*)pp)[1];
                float w = bspline(P0.x - cxw) * bspline(P0.y - cyw);
                float dpx = (cxw - P0.x) * DX;
                float dpy = (cyw - P0.y) * DX;
                svx += w * (P0.z + P1.x * dpx + P1.y * dpy);
                svy += w * (P0.w + P1.z * dpx + P1.w * dpy);
                sw  += w;
            }
        }
    } else {
        // fallback: global walk (R13 path)
        int c0 = max(cy - 2, 0);
        #pragma unroll
        for (int d = 0; d < 3; ++d) {
            int r = cx - 2 + d;
            if (r < 0 || r > NG - 1) continue;
            int row = r * NG;
            int s = cell_start[row + c0];
            int e = cell_start[row + cy + 1];
            const float io = (float)(2 - d);
            for (int t = s; t < e; ++t) {
                uint4 q = spay[t];
                float fxx = 0.5f + (float)(q.x & 0x3FFFu) * (1.0f / 16383.0f);
                float fxy = 0.5f + (float)((q.x >> 16) & 0x3FFFu) * (1.0f / 16383.0f);
                float fj = (float)((cy - (int)(q.x >> 30)) & 3);
                float wx;
                if (d == 0)      wx = 0.5f * (fxx - 0.5f) * (fxx - 0.5f);
                else if (d == 1) wx = 0.75f - (fxx - 1.0f) * (fxx - 1.0f);
                else             wx = 0.5f * (1.5f - fxx) * (1.5f - fxx);
                float wy = bspline(fxy - fj);
                float w = wx * wy;
                float2 vv = unpack2h(q.y);
                float2 aA = unpack2h(q.z);
                float2 aB = unpack2h(q.w);
                float dpx = (io - fxx) * DX;
                float dpy = (fj - fxy) * DX;
                svx += w * (vv.x + aA.x * dpx + aA.y * dpy);
                svy += w * (vv.y + aB.x * dpx + aB.y * dpy);
                sw  += w;
            }
        }
    }

    // fused grid update (P_MASS cancelled: gv = sv/sw)
    float vx = 0.0f, vy = 0.0f;
    if (sw > 0.0f) {
        float inv = 1.0f / sw;
        vx = svx * inv + GRAV_SCALE * grav[0];
        vy = svy * inv + GRAV_SCALE * grav[1];
        float dxp = apos[0] - DX * (float)cx;
        float dyp = apos[1] - DX * (float)cy;
        float nrm = sqrtf(dxp * dxp + dyp * dyp);
        float k = astr[0] * ATTR_SCALE / (0.01f + nrm);
        vx += dxp * k;
        vy += dyp * k;
        if (cx < 3 && vx < 0.0f) vx = 0.0f;
        if (cx > NG - 3 && vx > 0.0f) vx = 0.0f;
        if (cy < 3 && vy < 0.0f) vy = 0.0f;
        if (cy > NG - 3 && vy > 0.0f) vy = 0.0f;
    }
    ((float2*)gv)[cx * NG + cy] = make_float2(vx, vy);
}

// ---- K5: G2P (aligned float4-pair row reads, exact f32 weights, coalesced out) ----
__global__ __launch_bounds__(256)
void g2p_kernel(const float* __restrict__ x, const float* __restrict__ gv,
                float* __restrict__ outX, float* __restrict__ outV,
                float* __restrict__ outC)
{
    int p = blockIdx.x * blockDim.x + threadIdx.x;
    if (p >= NPART) return;

    const float2 xv = ((const float2*)x)[p];
    float xx = xv.x, xy = xv.y;
    float bxf = floorf(xx * INV_DX - 0.5f);
    float byf = floorf(xy * INV_DX - 0.5f);
    int bx = (int)bxf, by = (int)byf;
    float fxx = xx * INV_DX - bxf;
    float fxy = xy * INV_DX - byf;

    float wxs[3], wys[3];
    wxs[0] = 0.5f * (1.5f - fxx) * (1.5f - fxx);
    wxs[1] = 0.75f - (fxx - 1.0f) * (fxx - 1.0f);
    wxs[2] = 0.5f * (fxx - 0.5f) * (fxx - 0.5f);
    wys[0] = 0.5f * (1.5f - fxy) * (1.5f - fxy);
    wys[1] = 0.75f - (fxy - 1.0f) * (fxy - 1.0f);
    wys[2] = 0.5f * (fxy - 0.5f) * (fxy - 0.5f);

    // aligned column window: load cells [a0, a0+4) per row (covers by..by+2)
    int a0 = min(max(by & ~1, 0), NG - 4);
    bool odd = (by - a0) == 1;

    float nvx = 0.0f, nvy = 0.0f;
    float c00 = 0.0f, c01 = 0.0f, c10 = 0.0f, c11 = 0.0f;

    #pragma unroll
    for (int i = 0; i < 3; ++i) {
        int gi = min(max(bx + i, 0), NG - 1);
        float dpx = (float)i - fxx;
        const float4* rowp = (const float4*)(gv + gi * NG * 2 + a0 * 2);
        float4 A = rowp[0];
        float4 B = rowp[1];
        float g0x = odd ? A.z : A.x,  g0y = odd ? A.w : A.y;
        float g1x = odd ? B.x : A.z,  g1y = odd ? B.y : A.w;
        float g2x = odd ? B.z : B.x,  g2y = odd ? B.w : B.y;
        float w0 = wxs[i] * wys[0];
        float w1 = wxs[i] * wys[1];
        float w2 = wxs[i] * wys[2];
        float dpy0 = 0.0f - fxy, dpy1 = 1.0f - fxy, dpy2 = 2.0f - fxy;
        nvx += w0 * g0x + w1 * g1x + w2 * g2x;
        nvy += w0 * g0y + w1 * g1y + w2 * g2y;
        c00 += dpx * (w0 * g0x + w1 * g1x + w2 * g2x);
        c01 += w0 * g0x * dpy0 + w1 * g1x * dpy1 + w2 * g2x * dpy2;
        c10 += dpx * (w0 * g0y + w1 * g1y + w2 * g2y);
        c11 += w0 * g0y * dpy0 + w1 * g1y * dpy1 + w2 * g2y * dpy2;
    }
    float cs = 4.0f * INV_DX;
    ((float2*)outV)[p] = make_float2(nvx, nvy);
    ((float2*)outX)[p] = make_float2(xx + DT * nvx, xy + DT * nvy);
    ((float4*)outC)[p] = make_float4(cs * c00, cs * c01, cs * c10, cs * c11);
}

extern "C" void kernel_launch(void* const* d_in, const int* in_sizes, int n_in,
                              void* d_out, int out_size, void* d_ws, size_t ws_size,
                              hipStream_t stream)
{
    const float* x    = (const float*)d_in[0];
    const float* v    = (const float*)d_in[1];
    const float* C    = (const float*)d_in[2];
    const float* F    = (const float*)d_in[3];
    const float* Jp   = (const float*)d_in[4];
    const float* grav = (const float*)d_in[5];
    const float* astr = (const float*)d_in[6];
    const float* apos = (const float*)d_in[7];
    const int*   mat  = (const int*)d_in[8];

    float* out   = (float*)d_out;
    float* outX  = out;
    float* outV  = out + 2 * NPART;
    float* outC  = out + 4 * NPART;
    float* outF  = out + 8 * NPART;
    float* outJp = out + 12 * NPART;

    // workspace layout (4B units), ~36 MB. gv (8MB) aliases cnt + slack.
    int*   ws_i      = (int*)d_ws;
    int*   cnt       = ws_i;                       // NCELL (dead after scanc)
    float* gv        = (float*)d_ws;               // 2*NCELL floats (gather onward)
    int*   cell_start= ws_i + 2 * NCELL;           // NCELL+1
    int*   bsum      = cell_start + NCELL + 1;     // 1024
    int*   boff      = bsum + 1024;                // 1024
    int*   rank      = boff + 1024;                // NPART
    size_t off       = (size_t)(3 * NCELL + 2 * 1024 + 1 + NPART);
    off = (off + 3) & ~(size_t)3;                  // 16B align (4B units)
    uint4* spay      = (uint4*)(ws_i + off);       // NPART * 16B

    const int TB = 256;
    hipMemsetAsync(cnt, 0, (size_t)NCELL * sizeof(int), stream);
    count_kernel   <<<(NPART + TB - 1) / TB, TB, 0, stream>>>(x, cnt, rank);
    blocksum_kernel<<<NCELL / 1024, TB, 0, stream>>>(cnt, bsum);
    scanb_kernel   <<<1, 1024, 0, stream>>>(bsum, boff, cell_start);
    scanc_kernel   <<<NCELL / 1024, TB, 0, stream>>>(cnt, boff, cell_start);
    physics_scatter_kernel<<<(NPART + TB - 1) / TB, TB, 0, stream>>>(
        x, v, C, F, Jp, mat, cell_start, rank, spay, outF, outJp);
    p2g_tile_kernel<<<NBT * NBT, TB, 0, stream>>>(
        spay, cell_start, grav, astr, apos, gv);
    g2p_kernel     <<<(NPART + TB - 1) / TB, TB, 0, stream>>>(x, gv, outX, outV, outC);
}

// Round 15
// 180.833 us; speedup vs baseline: 1.0240x; 1.0240x over previous
//
#include <hip/hip_runtime.h>
#include <hip/hip_fp16.h>
#include <math.h>

namespace {
constexpr int   QUALITY = 8;
constexpr int   NPART   = 18000 * QUALITY * QUALITY;  // 1,152,000
constexpr int   NG      = 128 * QUALITY;              // 1024
constexpr int   NCELL   = NG * NG;                    // 1,048,576
constexpr int   CT      = 16;                         // gather tile side (cells)
constexpr int   NBT     = NG / CT;                    // 64
constexpr float DX      = 1.0f / (float)NG;
constexpr float INV_DX  = (float)NG;
constexpr float DT      = (float)(1e-4 / (double)QUALITY);
constexpr float MU0     = (float)(5000.0 / (2.0 * (1.0 + 0.2)));
constexpr float LAM0    = (float)(5000.0 * 0.2 / ((1.0 + 0.2) * (1.0 - 0.4)));
// stress scale divided by P_MASS (P_MASS cancels in gv = mom/mass):
constexpr float STRESS_RP  = (float)(-(1e-4 / 8.0) * 4.0 * 1024.0 * 1024.0);  // -52.4288
constexpr float GRAV_SCALE = (float)((1e-4 / 8.0) * 30.0);
constexpr float ATTR_SCALE = (float)((1e-4 / 8.0) * 100.0);

typedef int v4i __attribute__((ext_vector_type(4)));

__device__ __forceinline__ int2 base_of(float xx, float xy) {
    int bx = (int)floorf(xx * INV_DX - 0.5f);
    int by = (int)floorf(xy * INV_DX - 0.5f);
    bx = min(max(bx, 0), NG - 3);
    by = min(max(by, 0), NG - 3);
    return make_int2(bx, by);
}

__device__ __forceinline__ unsigned pack2h(float a, float b) {
    __half2 h = __floats2half2_rn(a, b);
    return *reinterpret_cast<unsigned*>(&h);
}
__device__ __forceinline__ float2 unpack2h(unsigned u) {
    __half2 h = *reinterpret_cast<__half2*>(&u);
    return __half22float2(h);
}

// quadratic B-spline weight, branchless: s = |fx - j|
__device__ __forceinline__ float bspline(float s) {
    s = fabsf(s);
    float a = 0.75f - s * s;
    float b = 1.5f - s;
    b = 0.5f * b * b;
    return (s < 0.5f) ? a : b;
}
}

// ---- K1: per-cell histogram; atomic return value IS the within-cell rank ----
__global__ __launch_bounds__(256)
void count_kernel(const float* __restrict__ x, int* __restrict__ cnt,
                  int* __restrict__ rank) {
    int p = blockIdx.x * blockDim.x + threadIdx.x;
    if (p >= NPART) return;
    const float2 xv = ((const float2*)x)[p];
    int2 b = base_of(xv.x, xv.y);
    rank[p] = atomicAdd(&cnt[b.x * NG + b.y], 1);
}

// ---- K2a: per-block (1024 cells) sums ----
__global__ __launch_bounds__(256)
void blocksum_kernel(const int* __restrict__ cnt, int* __restrict__ bsum) {
    __shared__ int sh[256];
    int t = threadIdx.x;
    int4 c = ((const int4*)cnt)[blockIdx.x * 256 + t];
    sh[t] = c.x + c.y + c.z + c.w;
    __syncthreads();
    for (int s = 128; s > 0; s >>= 1) {
        if (t < s) sh[t] += sh[t + s];
        __syncthreads();
    }
    if (t == 0) bsum[blockIdx.x] = sh[0];
}

// ---- K2b: exclusive scan of the 1024 block sums ----
__global__ __launch_bounds__(1024)
void scanb_kernel(const int* __restrict__ bsum, int* __restrict__ boff,
                  int* __restrict__ cell_start) {
    __shared__ int s[1024];
    int t = threadIdx.x;
    int v = bsum[t];
    s[t] = v;
    __syncthreads();
    for (int off = 1; off < 1024; off <<= 1) {
        int add = (t >= off) ? s[t - off] : 0;
        __syncthreads();
        s[t] += add;
        __syncthreads();
    }
    boff[t] = s[t] - v;
    if (t == 1023) cell_start[NCELL] = s[t];
}

// ---- K2c: per-block scan -> cell_start ----
__global__ __launch_bounds__(256)
void scanc_kernel(const int* __restrict__ cnt, const int* __restrict__ boff,
                  int* __restrict__ cell_start) {
    __shared__ int tsum[256];
    int t = threadIdx.x;
    int gbase4 = blockIdx.x * 256 + t;
    int4 c = ((const int4*)cnt)[gbase4];
    int s1 = c.x, s2 = s1 + c.y, s3 = s2 + c.z, tot = s3 + c.w;
    tsum[t] = tot;
    __syncthreads();
    for (int off = 1; off < 256; off <<= 1) {
        int add = (t >= off) ? tsum[t - off] : 0;
        __syncthreads();
        tsum[t] += add;
        __syncthreads();
    }
    int excl = tsum[t] - tot;
    int g = boff[blockIdx.x] + excl;
    ((int4*)cell_start)[gbase4] = make_int4(g, g + s1, g + s2, g + s3);
}

// ---- K3: fused physics + sorted 16B payload scatter (NO atomic: slot from rank) ----
// payload q.x: bits[13:0]=qx (fxx-0.5, 14b), [29:16]=qy, [31:30]=by&3
__global__ __launch_bounds__(256)
void physics_scatter_kernel(const float* __restrict__ x, const float* __restrict__ v,
                            const float* __restrict__ Cin, const float* __restrict__ Fin,
                            const float* __restrict__ Jpin, const int* __restrict__ mat,
                            const int* __restrict__ cell_start, const int* __restrict__ rank,
                            uint4* __restrict__ spay,
                            float* __restrict__ outF, float* __restrict__ outJp)
{
    int p = blockIdx.x * blockDim.x + threadIdx.x;
    if (p >= NPART) return;

    const float2 xv = ((const float2*)x)[p];
    const float2 vv = ((const float2*)v)[p];
    const float4 Cv = ((const float4*)Cin)[p];
    const float4 Fv = ((const float4*)Fin)[p];
    float xx = xv.x, xy = xv.y;
    float C00 = Cv.x, C01 = Cv.y, C10 = Cv.z, C11 = Cv.w;
    float F00 = Fv.x, F01 = Fv.y, F10 = Fv.z, F11 = Fv.w;

    // F = (I + DT*C) @ F
    float A00 = 1.0f + DT * C00, A01 = DT * C01, A10 = DT * C10, A11 = 1.0f + DT * C11;
    float G00 = A00 * F00 + A01 * F10;
    float G01 = A00 * F01 + A01 * F11;
    float G10 = A10 * F00 + A11 * F10;
    float G11 = A10 * F01 + A11 * F11;

    int m = mat[p];
    float Jp = Jpin[p];
    float h = fminf(fmaxf(expf(10.0f * (1.0f - Jp)), 0.1f), 5.0f);
    if (m == 1) h = 0.3f;
    float mu = (m == 0) ? 0.0f : MU0 * h;
    float la = LAM0 * h;

    // closed-form 2x2 SVD
    float Ee = 0.5f * (G00 + G11);
    float Hh = 0.5f * (G10 - G01);
    float Ff = 0.5f * (G00 - G11);
    float Gg = 0.5f * (G10 + G01);
    float Qq = sqrtf(Ee * Ee + Hh * Hh);
    float Rr = sqrtf(Ff * Ff + Gg * Gg);
    float s0 = Qq + Rr, s1 = Qq - Rr;
    float b1 = atan2f(Gg, Ff);
    float b2 = atan2f(Hh, Ee);
    float phi = 0.5f * (b1 + b2), th = 0.5f * (b1 - b2);
    float sphi, cphi, sth, cth;
    sincosf(phi, &sphi, &cphi);
    sincosf(th, &sth, &cth);

    float ns0 = s0, ns1 = s1;
    if (m == 2) {
        ns0 = fminf(fmaxf(s0, 1.0f - 2.5e-2f), 1.0f + 4.5e-3f);
        ns1 = fminf(fmaxf(s1, 1.0f - 2.5e-2f), 1.0f + 4.5e-3f);
        Jp = Jp * (s0 / ns0) * (s1 / ns1);
    }
    float J = ns0 * ns1;

    float FF00, FF01, FF10, FF11;
    if (m == 0) {
        float sj = sqrtf(J);
        FF00 = sj; FF01 = 0.0f; FF10 = 0.0f; FF11 = sj;
    } else if (m == 2) {
        FF00 = ns0 * cphi * cth + ns1 * sphi * sth;
        FF01 = ns0 * cphi * sth - ns1 * sphi * cth;
        FF10 = ns0 * sphi * cth - ns1 * cphi * sth;
        FF11 = ns0 * sphi * sth + ns1 * cphi * cth;
    } else {
        FF00 = G00; FF01 = G01; FF10 = G10; FF11 = G11;
    }

    // R = U V^T = rot(phi - th)
    float cr = cphi * cth + sphi * sth;
    float sr = sphi * cth - cphi * sth;

    float D00 = FF00 - cr,  D01 = FF01 + sr;
    float D10 = FF10 - sr,  D11 = FF11 - cr;
    float S00 = D00 * FF00 + D01 * FF01;
    float S01 = D00 * FF10 + D01 * FF11;
    float S10 = D10 * FF00 + D11 * FF01;
    float S11 = D10 * FF10 + D11 * FF11;
    float lj = la * J * (J - 1.0f);
    S00 = 2.0f * mu * S00 + lj;
    S01 = 2.0f * mu * S01;
    S10 = 2.0f * mu * S10;
    S11 = 2.0f * mu * S11 + lj;
    // affine / P_MASS  (P_MASS cancels in the grid normalize)
    float a00 = STRESS_RP * S00 + C00;
    float a01 = STRESS_RP * S01 + C01;
    float a10 = STRESS_RP * S10 + C10;
    float a11 = STRESS_RP * S11 + C11;

    ((float4*)outF)[p] = make_float4(FF00, FF01, FF10, FF11);
    outJp[p] = Jp;

    // fractional position (fx in [0.5,1.5)), 14-bit quantized
    float bxf = floorf(xx * INV_DX - 0.5f);
    float byf = floorf(xy * INV_DX - 0.5f);
    float fxx = xx * INV_DX - bxf;
    float fxy = xy * INV_DX - byf;
    unsigned qx = (unsigned)__float2int_rn((fxx - 0.5f) * 16383.0f);
    unsigned qy = (unsigned)__float2int_rn((fxy - 0.5f) * 16383.0f);

    int2 b = base_of(xx, xy);

    v4i payload;
    payload.x = (int)((qx & 0x3FFFu) | ((qy & 0x3FFFu) << 16) | (((unsigned)b.y & 3u) << 30));
    payload.y = (int)pack2h(vv.x, vv.y);
    payload.z = (int)pack2h(a00, a01);
    payload.w = (int)pack2h(a10, a11);

    int pos = cell_start[b.x * NG + b.y] + rank[p];   // no atomic
    __builtin_nontemporal_store(payload, (v4i*)&spay[pos]);
}

// ---- K4: atomic-free P2G gather (merged row ranges) + fused grid update ----
// XCD-aware tile swizzle: 4096 tiles -> 8 contiguous chunks of 512 (one per XCD),
// so neighboring tiles (sharing halo spay segments) stay in the same L2.
__global__ __launch_bounds__(256)
void p2g_gather_grid_kernel(const uint4* __restrict__ spay,
                            const int* __restrict__ cell_start,
                            const float* __restrict__ grav,
                            const float* __restrict__ astr,
                            const float* __restrict__ apos,
                            float* __restrict__ gv)
{
    int b = blockIdx.x;                    // 0..4095
    int tile = (b & 7) * 512 + (b >> 3);   // bijective XCD chunking
    int lr = threadIdx.x / CT;
    int lc = threadIdx.x % CT;
    int cx = (tile / NBT) * CT + lr;
    int cy = (tile % NBT) * CT + lc;

    float svx = 0.0f, svy = 0.0f, sw = 0.0f;
    int c0 = max(cy - 2, 0);
    float fcy = (float)cy;

    #pragma unroll
    for (int d = 0; d < 3; ++d) {
        int r = cx - 2 + d;                // particle base row; i = 2-d
        if (r < 0 || r > NG - 1) continue;
        int row = r * NG;
        int s = cell_start[row + c0];
        int e = cell_start[row + cy + 1];
        const float io = (float)(2 - d);
        for (int t = s; t < e; ++t) {
            uint4 q = spay[t];
            float fxx = 0.5f + (float)(q.x & 0x3FFFu) * (1.0f / 16383.0f);
            float fxy = 0.5f + (float)((q.x >> 16) & 0x3FFFu) * (1.0f / 16383.0f);
            float fj = (float)((cy - (int)(q.x >> 30)) & 3);   // j in {0,1,2}, guaranteed
            float wx;
            if (d == 0)      wx = 0.5f * (fxx - 0.5f) * (fxx - 0.5f);        // i=2
            else if (d == 1) wx = 0.75f - (fxx - 1.0f) * (fxx - 1.0f);       // i=1
            else             wx = 0.5f * (1.5f - fxx) * (1.5f - fxx);        // i=0
            float wy = bspline(fxy - fj);
            float w = wx * wy;
            float2 vv = unpack2h(q.y);
            float2 aA = unpack2h(q.z);
            float2 aB = unpack2h(q.w);
            float dpx = (io - fxx) * DX;
            float dpy = (fj - fxy) * DX;
            svx += w * (vv.x + aA.x * dpx + aA.y * dpy);
            svy += w * (vv.y + aB.x * dpx + aB.y * dpy);
            sw  += w;
        }
    }

    // fused grid update (P_MASS cancelled: gv = sv/sw)
    float vx = 0.0f, vy = 0.0f;
    if (sw > 0.0f) {
        float inv = 1.0f / sw;
        vx = svx * inv + GRAV_SCALE * grav[0];
        vy = svy * inv + GRAV_SCALE * grav[1];
        float dxp = apos[0] - DX * (float)cx;
        float dyp = apos[1] - DX * fcy;
        float nrm = sqrtf(dxp * dxp + dyp * dyp);
        float k = astr[0] * ATTR_SCALE / (0.01f + nrm);
        vx += dxp * k;
        vy += dyp * k;
        if (cx < 3 && vx < 0.0f) vx = 0.0f;
        if (cx > NG - 3 && vx > 0.0f) vx = 0.0f;
        if (cy < 3 && vy < 0.0f) vy = 0.0f;
        if (cy > NG - 3 && vy > 0.0f) vy = 0.0f;
    }
    ((float2*)gv)[cx * NG + cy] = make_float2(vx, vy);
}

// ---- K5: G2P (aligned float4-pair row reads, exact f32 weights, coalesced out) ----
__global__ __launch_bounds__(256)
void g2p_kernel(const float* __restrict__ x, const float* __restrict__ gv,
                float* __restrict__ outX, float* __restrict__ outV,
                float* __restrict__ outC)
{
    int p = blockIdx.x * blockDim.x + threadIdx.x;
    if (p >= NPART) return;

    const float2 xv = ((const float2*)x)[p];
    float xx = xv.x, xy = xv.y;
    float bxf = floorf(xx * INV_DX - 0.5f);
    float byf = floorf(xy * INV_DX - 0.5f);
    int bx = (int)bxf, by = (int)byf;
    float fxx = xx * INV_DX - bxf;
    float fxy = xy * INV_DX - byf;

    float wxs[3], wys[3];
    wxs[0] = 0.5f * (1.5f - fxx) * (1.5f - fxx);
    wxs[1] = 0.75f - (fxx - 1.0f) * (fxx - 1.0f);
    wxs[2] = 0.5f * (fxx - 0.5f) * (fxx - 0.5f);
    wys[0] = 0.5f * (1.5f - fxy) * (1.5f - fxy);
    wys[1] = 0.75f - (fxy - 1.0f) * (fxy - 1.0f);
    wys[2] = 0.5f * (fxy - 0.5f) * (fxy - 0.5f);

    // aligned column window: load cells [a0, a0+4) per row (covers by..by+2)
    int a0 = min(max(by & ~1, 0), NG - 4);
    bool odd = (by - a0) == 1;

    float nvx = 0.0f, nvy = 0.0f;
    float c00 = 0.0f, c01 = 0.0f, c10 = 0.0f, c11 = 0.0f;

    #pragma unroll
    for (int i = 0; i < 3; ++i) {
        int gi = min(max(bx + i, 0), NG - 1);
        float dpx = (float)i - fxx;
        const float4* rowp = (const float4*)(gv + gi * NG * 2 + a0 * 2);
        float4 A = rowp[0];
        float4 B = rowp[1];
        float g0x = odd ? A.z : A.x,  g0y = odd ? A.w : A.y;
        float g1x = odd ? B.x : A.z,  g1y = odd ? B.y : A.w;
        float g2x = odd ? B.z : B.x,  g2y = odd ? B.w : B.y;
        float w0 = wxs[i] * wys[0];
        float w1 = wxs[i] * wys[1];
        float w2 = wxs[i] * wys[2];
        float dpy0 = 0.0f - fxy, dpy1 = 1.0f - fxy, dpy2 = 2.0f - fxy;
        nvx += w0 * g0x + w1 * g1x + w2 * g2x;
        nvy += w0 * g0y + w1 * g1y + w2 * g2y;
        c00 += dpx * (w0 * g0x + w1 * g1x + w2 * g2x);
        c01 += w0 * g0x * dpy0 + w1 * g1x * dpy1 + w2 * g2x * dpy2;
        c10 += dpx * (w0 * g0y + w1 * g1y + w2 * g2y);
        c11 += w0 * g0y * dpy0 + w1 * g1y * dpy1 + w2 * g2y * dpy2;
    }
    float cs = 4.0f * INV_DX;
    ((float2*)outV)[p] = make_float2(nvx, nvy);
    ((float2*)outX)[p] = make_float2(xx + DT * nvx, xy + DT * nvy);
    ((float4*)outC)[p] = make_float4(cs * c00, cs * c01, cs * c10, cs * c11);
}

extern "C" void kernel_launch(void* const* d_in, const int* in_sizes, int n_in,
                              void* d_out, int out_size, void* d_ws, size_t ws_size,
                              hipStream_t stream)
{
    const float* x    = (const float*)d_in[0];
    const float* v    = (const float*)d_in[1];
    const float* C    = (const float*)d_in[2];
    const float* F    = (const float*)d_in[3];
    const float* Jp   = (const float*)d_in[4];
    const float* grav = (const float*)d_in[5];
    const float* astr = (const float*)d_in[6];
    const float* apos = (const float*)d_in[7];
    const int*   mat  = (const int*)d_in[8];

    float* out   = (float*)d_out;
    float* outX  = out;
    float* outV  = out + 2 * NPART;
    float* outC  = out + 4 * NPART;
    float* outF  = out + 8 * NPART;
    float* outJp = out + 12 * NPART;

    // workspace layout (4B units), ~36 MB. gv (8MB) aliases cnt + slack.
    int*   ws_i      = (int*)d_ws;
    int*   cnt       = ws_i;                       // NCELL (dead after scanc)
    float* gv        = (float*)d_ws;               // 2*NCELL floats (gather onward)
    int*   cell_start= ws_i + 2 * NCELL;           // NCELL+1
    int*   bsum      = cell_start + NCELL + 1;     // 1024
    int*   boff      = bsum + 1024;                // 1024
    int*   rank      = boff + 1024;                // NPART
    size_t off       = (size_t)(3 * NCELL + 2 * 1024 + 1 + NPART);
    off = (off + 3) & ~(size_t)3;                  // 16B align (4B units)
    uint4* spay      = (uint4*)(ws_i + off);       // NPART * 16B

    const int TB = 256;
    hipMemsetAsync(cnt, 0, (size_t)NCELL * sizeof(int), stream);
    count_kernel   <<<(NPART + TB - 1) / TB, TB, 0, stream>>>(x, cnt, rank);
    blocksum_kernel<<<NCELL / 1024, TB, 0, stream>>>(cnt, bsum);
    scanb_kernel   <<<1, 1024, 0, stream>>>(bsum, boff, cell_start);
    scanc_kernel   <<<NCELL / 1024, TB, 0, stream>>>(cnt, boff, cell_start);
    physics_scatter_kernel<<<(NPART + TB - 1) / TB, TB, 0, stream>>>(
        x, v, C, F, Jp, mat, cell_start, rank, spay, outF, outJp);
    p2g_gather_grid_kernel<<<NBT * NBT, TB, 0, stream>>>(
        spay, cell_start, grav, astr, apos, gv);
    g2p_kernel     <<<(NPART + TB - 1) / TB, TB, 0, stream>>>(x, gv, outX, outV, outC);
}